// Round 13
// baseline (218.038 us; speedup 1.0000x reference)
//
#include <hip/hip_runtime.h>
#include <math.h>

#ifndef M_PI
#define M_PI 3.14159265358979323846
#endif

#define NS 7      // NUM_SPHERICAL
#define NK 6      // NUM_RADIAL
#define BT 256    // threads per block
#define NC (NS*NS)   // 49
#define NR (NS*NK)   // 42
#define NF2 147      // float2 per triplet row (294/2)
#define NBLK 1536    // persistent grid: 6 blocks/CU x 256 CU

typedef float f32x2 __attribute__((ext_vector_type(2)));
typedef float f32x4 __attribute__((ext_vector_type(4)));

// tab layout (floats): [0..41] zeros (l*6+j), [42..83] norm, [84..132] coef(49)

// ---------------- setup (f32 hardware trig, ~1us) ---------------------------
__device__ void jl_pair_f(float x, int l, float& jl, float& jm1) {
  float s, c;
  __sincosf(x, &s, &c);
  float invx = 1.0f / x;
  float j0 = s * invx, jm = c * invx;
  if (l == 0) { jl = j0; jm1 = jm; return; }
  float j1 = (s * invx - c) * invx;
  for (int ll = 2; ll <= l; ++ll) {
    float t = (2.0f * ll - 1.0f) * invx * j1 - j0;
    j0 = j1; j1 = t;
  }
  jl = j1; jm1 = j0;
}

__global__ void setup_kernel(float* tab) {
  int id = threadIdx.x;
  if (id < NS * NK) {
    int l = id / NK, j = id % NK;
    float nu = l + 0.5f, mu = 4.0f * nu * nu;
    float b  = ((float)(j + 1) + 0.5f * nu - 0.25f) * (float)M_PI;
    float b8 = 8.0f * b;
    float x = b - (mu - 1.0f) / b8
                - 4.0f * (mu - 1.0f) * (7.0f * mu - 31.0f) / (3.0f * b8 * b8 * b8)
                - 32.0f * (mu - 1.0f) * (83.0f * mu * mu - 982.0f * mu + 3779.0f) /
                  (15.0f * b8 * b8 * b8 * b8 * b8);
    float jl, jm1;
    for (int it = 0; it < 5; ++it) {
      jl_pair_f(x, l, jl, jm1);
      float dj = jm1 - (l + 1.0f) / x * jl;   // j_l'(x)
      x -= jl / dj;
    }
    tab[id] = x;
    jl_pair_f(x, l, jl, jm1);
    float jp1 = (2.0f * l + 1.0f) / x * jl - jm1;   // j_{l+1}(x)
    tab[NS * NK + id] = sqrtf(2.0f) / fabsf(jp1);
  }
  if (id < NC) {
    double v;
    if (id == 0) {
      v = 0.5 / sqrt(M_PI);
    } else {
      int l = 1;
      while ((l + 1) * (l + 1) <= id) ++l;
      int m  = id - l * l - l;
      int am = m < 0 ? -m : m;
      double fr = 1.0;
      for (int i2 = l - am + 1; i2 <= l + am; ++i2) fr *= (double)i2;
      double pref = sqrt((2.0 * l + 1.0) / (4.0 * M_PI * fr));
      v = (m != 0) ? sqrt(2.0) * pref : pref;
    }
    tab[2 * NS * NK + id] = (float)v;
  }
}

// ---------------- main kernel: wave-persistent grid-stride ------------------
// 1536 blocks resident (6/CU). Tables once per block. Each wave grid-strides
// over 16-triplet tiles with a private LDS slice and NO barriers in the loop:
// tile k's stores stay outstanding across tile k+1's load+compute (only
// lgkmcnt waits in the loop; vmcnt is counted by the compiler for the loads).
__global__ __launch_bounds__(BT, 6) void torsion_kernel(
    const float* __restrict__ dist, const float* __restrict__ angle,
    const float* __restrict__ phi, const int* __restrict__ idx_kj,
    const float* __restrict__ tab, float* __restrict__ out, int T) {
  __shared__ float s_cbf[4][16][NC];                    // per-wave 16 x 49
  __shared__ __align__(8) float s_rbf[4][16][NR];       // per-wave 16 x 42
  __shared__ float s_dw[4][16];
  __shared__ float s_tab[133];
  __shared__ unsigned s_map2[NF2];   // packed: map(cc) | map((cc+1)%147)<<16

  const int tid  = threadIdx.x;
  const int w    = tid >> 6;
  const int lane = tid & 63;

  // ---- once per block: tables (only block-wide sync, before any stores) ----
  if (tid < 133) s_tab[tid] = tab[tid];
  if (tid < NF2) {
    auto mk = [](int cc) {
      int ii = (cc * 3121) >> 16;        // cc/21, cc<147
      int rem2 = cc - 21 * ii;
      int jj = (rem2 * 86) >> 8;         // rem2/3, rem2<21
      return (unsigned)((ii * NS + jj) | (rem2 << 8));
    };
    int cc1 = tid + 1; if (cc1 == NF2) cc1 = 0;
    s_map2[tid] = mk(tid) | (mk(cc1) << 16);
  }
  __syncthreads();

  const int ntiles = (T + 15) >> 4;
  const int nwaves = gridDim.x << 2;

  for (int tile = (blockIdx.x << 2) + w; tile < ntiles; tile += nwaves) {
    const int tw = tile << 4;            // first triplet of tile

    // ---- phase A: gather inputs for this wave's 16 triplets ----
    float a = 0.0f, ph = 0.0f;
    if (lane < 16) {
      int t = tw + lane;
      float dd = 1.0f;
      if (t < T) {
        dd = dist[idx_kj[t]] * 0.2f;     // /CUTOFF
        a  = angle[t];
        ph = phi[t];
      }
      s_dw[w][lane] = dd;
    }
    asm volatile("s_waitcnt lgkmcnt(0)" ::: "memory");   // s_dw visible in-wave

    // ---- phase B: compute (divergent halves, serialized within wave) ----
    if (lane < 16) {
      // cbf: one triplet per lane
      if (tw + lane < T) {
        float z, s;
        __sincosf(a, &s, &z);              // s=sin, z=cos
        float sp, cp;
        __sincosf(ph, &sp, &cp);
        float cmv[NS], smv[NS];
        cmv[0] = 1.0f; smv[0] = 0.0f;
        cmv[1] = cp;   smv[1] = sp;
#pragma unroll
        for (int m = 2; m < NS; ++m) {
          cmv[m] = 2.0f * cp * cmv[m - 1] - cmv[m - 2];
          smv[m] = 2.0f * cp * smv[m - 1] - smv[m - 2];
        }
        const float* coef = s_tab + 2 * NR;
        float* crow = s_cbf[w][lane];
        float pmm = 1.0f;
#pragma unroll
        for (int m = 0; m < NS; ++m) {
          float pl1 = pmm, pl2 = 0.0f;
#pragma unroll
          for (int l = m; l < NS; ++l) {
            float plm;
            if (l == m)          plm = pmm;
            else if (l == m + 1) plm = (float)(2 * m + 1) * z * pmm;
            else                 plm = ((float)(2 * l - 1) * z * pl1 -
                                        (float)(l + m - 1) * pl2) *
                                       (float)(1.0 / (double)(l - m));
            int cpn = l * l + l + m;
            if (m == 0) {
              crow[cpn] = coef[cpn] * plm;
            } else {
              crow[cpn] = coef[cpn] * cmv[m] * plm;
              crow[l * l + l - m] = coef[l * l + l - m] * smv[m] * plm;
            }
            pl2 = pl1; pl1 = plm;
          }
          pmm = (float)(-1 - 2 * m) * s * pmm;   // P[m+1][m+1]
        }
      }
    } else {
      // rbf: lanes 16..63 cover 16*42 = 672 = 14*48 items
      int j  = lane - 16;          // 0..47
      int t  = j / NR;             // 0 or 1
      int cc = j - NR * t;
      int i2 = j;
      float* rlin = &s_rbf[w][0][0];
#pragma unroll 2
      for (int it = 0; it < 14; ++it) {
        int l = (cc * 43) >> 8;      // cc/6 for cc<42
        float x = s_dw[w][t] * s_tab[cc];
        float sx, cx;
        __sincosf(x, &sx, &cx);
        float invx = 1.0f / x;
        float jm = sx * invx;
        float jc;
        if (l == 0) jc = jm;
        else {
          jc = (sx * invx - cx) * invx;
#pragma unroll
          for (int ll = 2; ll <= 6; ++ll) {
            if (ll <= l) {
              float tt = (float)(2 * ll - 1) * invx * jc - jm;
              jm = jc; jc = tt;
            }
          }
        }
        rlin[i2] = s_tab[NR + cc] * jc;
        i2 += 48;
        cc += 6; t += 1;             // 48 = 42 + 6
        if (cc >= NR) { cc -= NR; ++t; }
      }
    }
    asm volatile("s_waitcnt lgkmcnt(0)" ::: "memory");   // compute LDS visible
    __builtin_amdgcn_sched_barrier(0);

    // ---- phase C: store 16 triplets = 1176 f32x4, monotonic, 6-deep bursts --
    const f32x2* r2 = (const f32x2*)&s_rbf[w][0][0];   // row stride 21 f32x2
    const int nt_w = min(16, T - tw);

    if (nt_w == 16) {
      int p = 0, k = lane;              // lane < 147 always
      int cc = k << 1;                  // 2k < 128 < 147
      f32x4* o4 = (f32x4*)out + (size_t)tile * 1176 + lane;

      auto GATHER = [&]() -> f32x4 {
        int t2 = p << 1;
        int ta = t2 + (k >= 74 ? 1 : 0);    // local row of first f32x2 (c2=2k)
        int tb = t2 + (k >= 73 ? 1 : 0);    // local row of second f32x2
        unsigned mp = s_map2[cc];
        unsigned i0 = mp & 0xffu,          r0 = (mp >> 8) & 0xffu;
        unsigned i1 = (mp >> 16) & 0xffu,  r1 = mp >> 24;
        float cv0 = s_cbf[w][ta][i0];
        f32x2 rv0 = r2[ta * 21 + r0];
        float cv1 = s_cbf[w][tb][i1];
        f32x2 rv1 = r2[tb * 21 + r1];
        f32x4 ov = {cv0 * rv0.x, cv0 * rv0.y, cv1 * rv1.x, cv1 * rv1.y};
        k += 64;  if (k >= 147) { k -= 147; ++p; }
        cc += 128; if (cc >= NF2) cc -= NF2;
        return ov;
      };

      f32x4 ov[6];
#pragma unroll
      for (int g = 0; g < 3; ++g) {
#pragma unroll
        for (int j = 0; j < 6; ++j) ov[j] = GATHER();
#pragma unroll
        for (int j = 0; j < 6; ++j)
          __builtin_nontemporal_store(ov[j], o4 + (g * 6 + j) * 64);
      }
      if (lane < 24) {                   // it = 18: last 24 f32x4 of the wave
        f32x4 last = GATHER();
        __builtin_nontemporal_store(last, o4 + 18 * 64);
      }
    } else if (nt_w > 0) {
      // partial tile (only if T % 16 != 0): float2 path over valid triplets
      f32x2* o2 = (f32x2*)out + (size_t)tw * NF2;
      int tot = nt_w * NF2;
      for (int i = lane; i < tot; i += 64) {
        int t  = i / NF2;
        int c2 = i - NF2 * t;
        unsigned mp = s_map2[c2] & 0xffffu;
        float cv = s_cbf[w][t][mp & 0xffu];
        f32x2 rv = r2[t * 21 + (mp >> 8)];
        f32x2 ov = cv * rv;
        __builtin_nontemporal_store(ov, o2 + i);
      }
    }

    // drain this tile's LDS reads before next iteration overwrites the slice
    // (global stores intentionally left in flight — no vmcnt here)
    asm volatile("s_waitcnt lgkmcnt(0)" ::: "memory");
    __builtin_amdgcn_sched_barrier(0);
  }
}

// ---------------- launch ----------------------------------------------------
extern "C" void kernel_launch(void* const* d_in, const int* in_sizes, int n_in,
                              void* d_out, int out_size, void* d_ws, size_t ws_size,
                              hipStream_t stream) {
  const float* dist  = (const float*)d_in[0];
  const float* angle = (const float*)d_in[1];
  const float* phi   = (const float*)d_in[2];
  const int*   idx   = (const int*)d_in[3];
  float* out = (float*)d_out;
  float* tab = (float*)d_ws;          // 133 floats
  int T = in_sizes[1];

  hipLaunchKernelGGL(setup_kernel, dim3(1), dim3(64), 0, stream, tab);
  int ntiles = (T + 15) / 16;
  int nwavesneeded = (ntiles + 3) / 4;           // 4 waves per block
  int nb = nwavesneeded < NBLK ? nwavesneeded : NBLK;
  hipLaunchKernelGGL(torsion_kernel, dim3(nb), dim3(BT), 0, stream,
                     dist, angle, phi, idx, tab, out, T);
}

// Round 14
// 122.886 us; speedup vs baseline: 1.7743x; 1.7743x over previous
//
#include <hip/hip_runtime.h>
#include <math.h>

#ifndef M_PI
#define M_PI 3.14159265358979323846
#endif

#define NS 7      // NUM_SPHERICAL
#define NK 6      // NUM_RADIAL
#define GT 64     // triplets per block
#define BT 256    // threads per block
#define NC (NS*NS)   // 49
#define NR (NS*NK)   // 42
#define NF2 147      // float2 per triplet row (294/2)

typedef float f32x2 __attribute__((ext_vector_type(2)));
typedef float f32x4 __attribute__((ext_vector_type(4)));

// tab layout (floats): [0..41] zeros (l*6+j), [42..83] norm, [84..132] coef(49)

// ---------------- setup (f32 hardware trig, ~1us) ---------------------------
__device__ void jl_pair_f(float x, int l, float& jl, float& jm1) {
  float s, c;
  __sincosf(x, &s, &c);
  float invx = 1.0f / x;
  float j0 = s * invx, jm = c * invx;
  if (l == 0) { jl = j0; jm1 = jm; return; }
  float j1 = (s * invx - c) * invx;
  for (int ll = 2; ll <= l; ++ll) {
    float t = (2.0f * ll - 1.0f) * invx * j1 - j0;
    j0 = j1; j1 = t;
  }
  jl = j1; jm1 = j0;
}

__global__ void setup_kernel(float* tab) {
  int id = threadIdx.x;
  if (id < NS * NK) {
    int l = id / NK, j = id % NK;
    float nu = l + 0.5f, mu = 4.0f * nu * nu;
    float b  = ((float)(j + 1) + 0.5f * nu - 0.25f) * (float)M_PI;
    float b8 = 8.0f * b;
    float x = b - (mu - 1.0f) / b8
                - 4.0f * (mu - 1.0f) * (7.0f * mu - 31.0f) / (3.0f * b8 * b8 * b8)
                - 32.0f * (mu - 1.0f) * (83.0f * mu * mu - 982.0f * mu + 3779.0f) /
                  (15.0f * b8 * b8 * b8 * b8 * b8);
    float jl, jm1;
    for (int it = 0; it < 5; ++it) {
      jl_pair_f(x, l, jl, jm1);
      float dj = jm1 - (l + 1.0f) / x * jl;   // j_l'(x)
      x -= jl / dj;
    }
    tab[id] = x;
    jl_pair_f(x, l, jl, jm1);
    float jp1 = (2.0f * l + 1.0f) / x * jl - jm1;   // j_{l+1}(x)
    tab[NS * NK + id] = sqrtf(2.0f) / fabsf(jp1);
  }
  if (id < NC) {
    double v;
    if (id == 0) {
      v = 0.5 / sqrt(M_PI);
    } else {
      int l = 1;
      while ((l + 1) * (l + 1) <= id) ++l;
      int m  = id - l * l - l;
      int am = m < 0 ? -m : m;
      double fr = 1.0;
      for (int i2 = l - am + 1; i2 <= l + am; ++i2) fr *= (double)i2;
      double pref = sqrt((2.0 * l + 1.0) / (4.0 * M_PI * fr));
      v = (m != 0) ? sqrt(2.0) * pref : pref;
    }
    tab[2 * NS * NK + id] = (float)v;
  }
}

// ---------------- main kernel (round-11 best: 122.8us) ----------------------
__global__ __launch_bounds__(BT, 6) void torsion_kernel(
    const float* __restrict__ dist, const float* __restrict__ angle,
    const float* __restrict__ phi, const int* __restrict__ idx_kj,
    const float* __restrict__ tab, float* __restrict__ out, int T) {
  __shared__ float s_cbf[GT][NC];                       // 64 x 49
  __shared__ __align__(8) float s_rbf[GT][NR];          // 64 x 42
  __shared__ float s_d[GT];
  __shared__ float s_tab[133];
  __shared__ unsigned s_map2[NF2];   // packed: map(cc) | map((cc+1)%147)<<16

  const int tid = threadIdx.x;
  const int t0  = blockIdx.x * GT;
  const int nt  = min(GT, T - t0);

  // ---- phase 0: input loads + LDS tables ----
  float a = 0.0f, ph = 0.0f;
  if (tid < GT) {
    int t = t0 + tid;
    float dd = 1.0f;
    if (t < T) {
      dd = dist[idx_kj[t]] * 0.2f;   // /CUTOFF
      a  = angle[t];
      ph = phi[t];
    }
    s_d[tid] = dd;
  }
  if (tid < 133) s_tab[tid] = tab[tid];
  if (tid < NF2) {
    // map(cc): ii=cc/21, rem2=cc-21*ii, jj=rem2/3 -> (ii*7+jj) | rem2<<8
    auto mk = [](int cc) {
      int ii = (cc * 3121) >> 16;        // cc/21, cc<147
      int rem2 = cc - 21 * ii;
      int jj = (rem2 * 86) >> 8;         // rem2/3, rem2<21
      return (unsigned)((ii * NS + jj) | (rem2 << 8));
    };
    int cc1 = tid + 1; if (cc1 == NF2) cc1 = 0;
    s_map2[tid] = mk(tid) | (mk(cc1) << 16);
  }
  __syncthreads();

  if (tid < GT) {
    // ---- cbf: lanes 0..63, per-m streaming Legendre ----
    if (t0 + tid < T) {
      float z, s;
      __sincosf(a, &s, &z);              // s=sin, z=cos
      float sp, cp;
      __sincosf(ph, &sp, &cp);
      float cmv[NS], smv[NS];
      cmv[0] = 1.0f; smv[0] = 0.0f;
      cmv[1] = cp;   smv[1] = sp;
#pragma unroll
      for (int m = 2; m < NS; ++m) {
        cmv[m] = 2.0f * cp * cmv[m - 1] - cmv[m - 2];
        smv[m] = 2.0f * cp * smv[m - 1] - smv[m - 2];
      }
      const float* coef = s_tab + 2 * NR;
      float* crow = s_cbf[tid];
      float pmm = 1.0f;
#pragma unroll
      for (int m = 0; m < NS; ++m) {
        float pl1 = pmm, pl2 = 0.0f;
#pragma unroll
        for (int l = m; l < NS; ++l) {
          float plm;
          if (l == m)          plm = pmm;
          else if (l == m + 1) plm = (float)(2 * m + 1) * z * pmm;
          else                 plm = ((float)(2 * l - 1) * z * pl1 -
                                      (float)(l + m - 1) * pl2) *
                                     (float)(1.0 / (double)(l - m));
          int cpn = l * l + l + m;
          if (m == 0) {
            crow[cpn] = coef[cpn] * plm;
          } else {
            crow[cpn] = coef[cpn] * cmv[m] * plm;
            crow[l * l + l - m] = coef[l * l + l - m] * smv[m] * plm;
          }
          pl2 = pl1; pl1 = plm;
        }
        pmm = (float)(-1 - 2 * m) * s * pmm;   // P[m+1][m+1]
      }
    }
  } else {
    // ---- rbf: threads 64..255 cover 64*42 = 2688 = 14*192 items ----
    int j  = tid - 64;
    int t  = j / NR;
    int cc = j - NR * t;
    int i2 = j;
    float* rlin = &s_rbf[0][0];
#pragma unroll 2
    for (int it = 0; it < 14; ++it) {
      int l = (cc * 43) >> 8;      // cc/6 for cc<42
      float x = s_d[t] * s_tab[cc];
      float sx, cx;
      __sincosf(x, &sx, &cx);
      float invx = 1.0f / x;
      float jm = sx * invx;
      float jc;
      if (l == 0) jc = jm;
      else {
        jc = (sx * invx - cx) * invx;
#pragma unroll
        for (int ll = 2; ll <= 6; ++ll) {
          if (ll <= l) {
            float tt = (float)(2 * ll - 1) * invx * jc - jm;
            jm = jc; jc = tt;
          }
        }
      }
      rlin[i2] = s_tab[NR + cc] * jc;
      i2 += 192;
      cc += 24; t += 4;            // 192 = 4*42 + 24
      if (cc >= NR) { cc -= NR; ++t; }
    }
  }
  __syncthreads();

  // ---- store: wave-contiguous monotonic streams, 6-deep register bursts ----
  const f32x2* r2 = (const f32x2*)&s_rbf[0][0];   // row stride 21 f32x2

  if (nt == GT) {
    const int w    = tid >> 6;
    const int lane = tid & 63;
    const int n0   = w * 1176 + lane;
    int p = n0 / 147;                 // triplet-pair index (0..31)
    int k = n0 - 147 * p;             // f32x4 index within the 588-float pair
    int cc = k << 1; if (cc >= NF2) cc -= NF2;   // (2k) mod 147

    f32x4* o4 = (f32x4*)out + (size_t)blockIdx.x * 4704 + n0;

    auto GATHER = [&]() -> f32x4 {
      int t2 = p << 1;
      int ta = t2 + (k >= 74 ? 1 : 0);    // row of first f32x2 (c2=2k)
      int tb = t2 + (k >= 73 ? 1 : 0);    // row of second f32x2 (c2=2k+1)
      unsigned mp = s_map2[cc];
      unsigned i0 = mp & 0xffu,          r0 = (mp >> 8) & 0xffu;
      unsigned i1 = (mp >> 16) & 0xffu,  r1 = mp >> 24;
      float cv0 = s_cbf[ta][i0];
      f32x2 rv0 = r2[ta * 21 + r0];
      float cv1 = s_cbf[tb][i1];
      f32x2 rv1 = r2[tb * 21 + r1];
      f32x4 ov = {cv0 * rv0.x, cv0 * rv0.y, cv1 * rv1.x, cv1 * rv1.y};
      // advance walk: n += 64
      k += 64;  if (k >= 147) { k -= 147; ++p; }
      cc += 128; if (cc >= NF2) cc -= NF2;
      return ov;
    };

    f32x4 ov[6];
#pragma unroll
    for (int g = 0; g < 3; ++g) {
#pragma unroll
      for (int j = 0; j < 6; ++j) ov[j] = GATHER();
#pragma unroll
      for (int j = 0; j < 6; ++j)
        __builtin_nontemporal_store(ov[j], o4 + (g * 6 + j) * 64);
    }
    if (lane < 24) {                   // it = 18: last 24 f32x4 of the wave
      f32x4 last = GATHER();
      __builtin_nontemporal_store(last, o4 + 18 * 64);
    }
  } else {
    // tail block: float2 path, any nt
    f32x2* o2 = (f32x2*)out + (size_t)t0 * NF2;
    int tot = nt * NF2;
    for (int i = tid; i < tot; i += BT) {
      int t  = i / NF2;
      int c2 = i - NF2 * t;
      unsigned mp = s_map2[c2] & 0xffffu;
      float cv = s_cbf[t][mp & 0xffu];
      f32x2 rv = r2[t * 21 + (mp >> 8)];
      f32x2 ov = cv * rv;
      __builtin_nontemporal_store(ov, o2 + i);
    }
  }
}

// ---------------- launch ----------------------------------------------------
extern "C" void kernel_launch(void* const* d_in, const int* in_sizes, int n_in,
                              void* d_out, int out_size, void* d_ws, size_t ws_size,
                              hipStream_t stream) {
  const float* dist  = (const float*)d_in[0];
  const float* angle = (const float*)d_in[1];
  const float* phi   = (const float*)d_in[2];
  const int*   idx   = (const int*)d_in[3];
  float* out = (float*)d_out;
  float* tab = (float*)d_ws;          // 133 floats
  int T = in_sizes[1];

  hipLaunchKernelGGL(setup_kernel, dim3(1), dim3(64), 0, stream, tab);
  int nb = (T + GT - 1) / GT;
  hipLaunchKernelGGL(torsion_kernel, dim3(nb), dim3(BT), 0, stream,
                     dist, angle, phi, idx, tab, out, T);
}